// Round 3
// baseline (150.262 us; speedup 1.0000x reference)
//
#include <hip/hip_runtime.h>

#define N_H 8192
#define RANK 8
#define BATCH 2048
#define CPR (N_H / 4)        // 2048 float4 chunks per row

// ---------------- Kernel A: P_part[s][b][r] = sum_{n in seg s} tanh(h[b,n]) * V[r,n]
#define RB_A 4
#define SEG_A 2
#define BLK_A 512
#define CSEG (CPR / SEG_A)           // 1024 float4 per segment
#define ITER_A (CSEG / BLK_A)        // 2
#define NWAVES_A (BLK_A / 64)        // 8

__device__ __forceinline__ float fast_tanh(float x) {
    float e = __expf(2.0f * x);
    return 1.0f - 2.0f / (e + 1.0f);
}

__global__ __launch_bounds__(BLK_A) void rnn_phase1(
    const float* __restrict__ h, const float* __restrict__ V,
    float* __restrict__ Ppart)
{
    const int t = threadIdx.x;
    const int seg = blockIdx.x & (SEG_A - 1);
    const int b0 = (blockIdx.x >> 1) * RB_A;
    const float4* __restrict__ H4 = (const float4*)h;
    const float4* __restrict__ V4 = (const float4*)V;   // [RANK][CPR]

    float acc[RB_A][RANK];
    #pragma unroll
    for (int j = 0; j < RB_A; ++j)
        #pragma unroll
        for (int r = 0; r < RANK; ++r) acc[j][r] = 0.0f;

    #pragma unroll
    for (int i = 0; i < ITER_A; ++i) {
        const int c = seg * CSEG + i * BLK_A + t;
        float4 v4[RANK];
        #pragma unroll
        for (int r = 0; r < RANK; ++r) v4[r] = V4[r * CPR + c];
        #pragma unroll
        for (int j = 0; j < RB_A; ++j) {
            float4 h4 = H4[(size_t)(b0 + j) * CPR + c];
            float tx = fast_tanh(h4.x), ty = fast_tanh(h4.y);
            float tz = fast_tanh(h4.z), tw = fast_tanh(h4.w);
            #pragma unroll
            for (int r = 0; r < RANK; ++r)
                acc[j][r] += tx * v4[r].x + ty * v4[r].y + tz * v4[r].z + tw * v4[r].w;
        }
    }

    // wave-level butterfly reduce (all lanes end with the wave sum)
    #pragma unroll
    for (int j = 0; j < RB_A; ++j)
        #pragma unroll
        for (int r = 0; r < RANK; ++r) {
            float v = acc[j][r];
            #pragma unroll
            for (int off = 32; off >= 1; off >>= 1)
                v += __shfl_xor(v, off, 64);
            acc[j][r] = v;
        }

    __shared__ float red[NWAVES_A][RB_A][RANK];
    const int wave = t >> 6, lane = t & 63;
    if (lane == 0) {
        #pragma unroll
        for (int j = 0; j < RB_A; ++j)
            #pragma unroll
            for (int r = 0; r < RANK; ++r) red[wave][j][r] = acc[j][r];
    }
    __syncthreads();
    if (t < RB_A * RANK) {
        const int j = t >> 3, r = t & 7;
        float s = 0.0f;
        #pragma unroll
        for (int w = 0; w < NWAVES_A; ++w) s += red[w][j][r];
        Ppart[((size_t)seg * BATCH + b0 + j) * RANK + r] = s;
    }
}

// ---------------- Kernel B: out = 0.99*h + 0.01*ff + sum_r phat[b][r]*U[n][r]
#define RB_B 4
#define SEG_B 2
#define BLK_B 512
#define CSEG_B (CPR / SEG_B)
#define ITER_B (CSEG_B / BLK_B)      // 2

__global__ __launch_bounds__(BLK_B) void rnn_phase2(
    const float* __restrict__ ff, const float* __restrict__ h,
    const float* __restrict__ U, const float* __restrict__ Ppart,
    float* __restrict__ out)
{
    const int t = threadIdx.x;
    const int seg = blockIdx.x & (SEG_B - 1);
    const int b0 = (blockIdx.x >> 1) * RB_B;
    const float4* __restrict__ H4 = (const float4*)h;
    const float4* __restrict__ U4 = (const float4*)U;   // [N_H][RANK/4] pairs
    const float4* __restrict__ FF4 = (const float4*)ff;
    float4* __restrict__ O4 = (float4*)out;

    constexpr float INV_N = 1.0f / (float)N_H;
    constexpr float CA = 1.0f - 0.01f;
    constexpr float CB = 0.01f;

    // wave-uniform indices -> compiler emits scalar loads (SGPR-resident p)
    float p[RB_B][RANK];
    #pragma unroll
    for (int j = 0; j < RB_B; ++j)
        #pragma unroll
        for (int r = 0; r < RANK; ++r) {
            float s = Ppart[((size_t)0 * BATCH + b0 + j) * RANK + r]
                    + Ppart[((size_t)1 * BATCH + b0 + j) * RANK + r];
            p[j][r] = s * (CB * INV_N);   // prescale: fold 0.01/N into p
        }

    #pragma unroll
    for (int i = 0; i < ITER_B; ++i) {
        const int c = seg * CSEG_B + i * BLK_B + t;
        float4 f4 = FF4[c];
        float4 u[8];
        #pragma unroll
        for (int k = 0; k < 8; ++k) u[k] = U4[(size_t)c * 8 + k];
        #pragma unroll
        for (int j = 0; j < RB_B; ++j) {
            float4 h4 = H4[(size_t)(b0 + j) * CPR + c];
            float s0 = p[j][0]*u[0].x + p[j][1]*u[0].y + p[j][2]*u[0].z + p[j][3]*u[0].w
                     + p[j][4]*u[1].x + p[j][5]*u[1].y + p[j][6]*u[1].z + p[j][7]*u[1].w;
            float s1 = p[j][0]*u[2].x + p[j][1]*u[2].y + p[j][2]*u[2].z + p[j][3]*u[2].w
                     + p[j][4]*u[3].x + p[j][5]*u[3].y + p[j][6]*u[3].z + p[j][7]*u[3].w;
            float s2 = p[j][0]*u[4].x + p[j][1]*u[4].y + p[j][2]*u[4].z + p[j][3]*u[4].w
                     + p[j][4]*u[5].x + p[j][5]*u[5].y + p[j][6]*u[5].z + p[j][7]*u[5].w;
            float s3 = p[j][0]*u[6].x + p[j][1]*u[6].y + p[j][2]*u[6].z + p[j][3]*u[6].w
                     + p[j][4]*u[7].x + p[j][5]*u[7].y + p[j][6]*u[7].z + p[j][7]*u[7].w;
            float4 o;
            o.x = CA * h4.x + CB * f4.x + s0;
            o.y = CA * h4.y + CB * f4.y + s1;
            o.z = CA * h4.z + CB * f4.z + s2;
            o.w = CA * h4.w + CB * f4.w + s3;
            O4[(size_t)(b0 + j) * CPR + c] = o;
        }
    }
}

extern "C" void kernel_launch(void* const* d_in, const int* in_sizes, int n_in,
                              void* d_out, int out_size, void* d_ws, size_t ws_size,
                              hipStream_t stream) {
    const float* ff = (const float*)d_in[0];   // [8192]
    const float* h  = (const float*)d_in[1];   // [2048, 8192]
    const float* U  = (const float*)d_in[2];   // [8192, 8]
    const float* V  = (const float*)d_in[3];   // [8, 8192]
    float* out = (float*)d_out;                // [2048, 8192]
    float* Ppart = (float*)d_ws;               // [SEG_A][BATCH][RANK] = 128 KB

    rnn_phase1<<<dim3((BATCH / RB_A) * SEG_A), dim3(BLK_A), 0, stream>>>(h, V, Ppart);
    rnn_phase2<<<dim3((BATCH / RB_B) * SEG_B), dim3(BLK_B), 0, stream>>>(ff, h, U, Ppart, out);
}

// Round 5
// 143.211 us; speedup vs baseline: 1.0492x; 1.0492x over previous
//
#include <hip/hip_runtime.h>

#define N_H 8192
#define RANK 8
#define BATCH 2048
#define CPR (N_H / 4)        // 2048 float4 chunks per row

// ---------------- Kernel A: P_part[s][b][r] = sum_{n in seg s} tanh(h[b,n]) * V[r,n]
#define RB_A 4
#define SEG_A 2
#define BLK_A 512
#define CSEG (CPR / SEG_A)           // 1024 float4 per segment
#define ITER_A (CSEG / BLK_A)        // 2
#define NWAVES_A (BLK_A / 64)        // 8

__device__ __forceinline__ float fast_tanh(float x) {
    float e = __expf(2.0f * x);
    return 1.0f - 2.0f / (e + 1.0f);
}

__global__ __launch_bounds__(BLK_A) void rnn_phase1(
    const float* __restrict__ h, const float* __restrict__ V,
    float* __restrict__ Ppart)
{
    const int t = threadIdx.x;
    const int lane = t & 63;
    const int wave = t >> 6;
    const int seg = blockIdx.x & (SEG_A - 1);
    const int b0 = (blockIdx.x >> 1) * RB_A;
    const float4* __restrict__ H4 = (const float4*)h;
    const float4* __restrict__ V4 = (const float4*)V;   // [RANK][CPR]

    // accumulators flattened: k = j*RANK + r
    float v32[RB_A * RANK];
    #pragma unroll
    for (int k = 0; k < RB_A * RANK; ++k) v32[k] = 0.0f;

    #pragma unroll
    for (int i = 0; i < ITER_A; ++i) {
        const int c = seg * CSEG + i * BLK_A + t;
        float4 v4[RANK];
        #pragma unroll
        for (int r = 0; r < RANK; ++r) v4[r] = V4[r * CPR + c];
        #pragma unroll
        for (int j = 0; j < RB_A; ++j) {
            float4 h4 = H4[(size_t)(b0 + j) * CPR + c];
            float tx = fast_tanh(h4.x), ty = fast_tanh(h4.y);
            float tz = fast_tanh(h4.z), tw = fast_tanh(h4.w);
            #pragma unroll
            for (int r = 0; r < RANK; ++r)
                v32[j * RANK + r] += tx * v4[r].x + ty * v4[r].y
                                   + tz * v4[r].z + tw * v4[r].w;
        }
    }

    // ---- packed wave reduction: 32 values -> lane l holds S_{l&31}
    // stage(off): c = bit?b:a ; c += shfl_xor(bit?a:b, off); halves count.
    float v16[16];
    {
        const bool hi = (lane & 1);
        #pragma unroll
        for (int m = 0; m < 16; ++m) {
            float a = v32[2 * m], b = v32[2 * m + 1];
            float keep = hi ? b : a;
            float send = hi ? a : b;
            v16[m] = keep + __shfl_xor(send, 1, 64);
        }
    }
    float v8[8];
    {
        const bool hi = (lane & 2);
        #pragma unroll
        for (int m = 0; m < 8; ++m) {
            float a = v16[2 * m], b = v16[2 * m + 1];
            float keep = hi ? b : a;
            float send = hi ? a : b;
            v8[m] = keep + __shfl_xor(send, 2, 64);
        }
    }
    float v4r[4];
    {
        const bool hi = (lane & 4);
        #pragma unroll
        for (int m = 0; m < 4; ++m) {
            float a = v8[2 * m], b = v8[2 * m + 1];
            float keep = hi ? b : a;
            float send = hi ? a : b;
            v4r[m] = keep + __shfl_xor(send, 4, 64);
        }
    }
    float v2r[2];
    {
        const bool hi = (lane & 8);
        #pragma unroll
        for (int m = 0; m < 2; ++m) {
            float a = v4r[2 * m], b = v4r[2 * m + 1];
            float keep = hi ? b : a;
            float send = hi ? a : b;
            v2r[m] = keep + __shfl_xor(send, 8, 64);
        }
    }
    float v1;
    {
        const bool hi = (lane & 16);
        float a = v2r[0], b = v2r[1];
        float keep = hi ? b : a;
        float send = hi ? a : b;
        v1 = keep + __shfl_xor(send, 16, 64);
    }
    v1 += __shfl_xor(v1, 32, 64);   // lane l (l<32) now holds S_{l&31}

    // ---- cross-wave combine (conflict-free [8][32] tile)
    __shared__ float red[NWAVES_A][32];
    if (lane < 32) red[wave][lane] = v1;
    __syncthreads();
    if (t < 32) {
        float s = 0.0f;
        #pragma unroll
        for (int w = 0; w < NWAVES_A; ++w) s += red[w][t];
        // k = t: j = t>>3, r = t&7
        Ppart[((size_t)seg * BATCH + b0 + (t >> 3)) * RANK + (t & 7)] = s;
    }
}

// ---------------- Kernel B: out = 0.99*h + 0.01*ff + sum_r phat[b][r]*U[n][r]
#define RB_B 4
#define SEG_B 2
#define BLK_B 512
#define CSEG_B (CPR / SEG_B)
#define ITER_B (CSEG_B / BLK_B)      // 2

__global__ __launch_bounds__(BLK_B) void rnn_phase2(
    const float* __restrict__ ff, const float* __restrict__ h,
    const float* __restrict__ U, const float* __restrict__ Ppart,
    float* __restrict__ out)
{
    const int t = threadIdx.x;
    const int seg = blockIdx.x & (SEG_B - 1);
    const int b0 = (blockIdx.x >> 1) * RB_B;
    const float4* __restrict__ H4 = (const float4*)h;
    const float4* __restrict__ U4 = (const float4*)U;   // [N_H][RANK/4] pairs
    const float4* __restrict__ FF4 = (const float4*)ff;
    float4* __restrict__ O4 = (float4*)out;

    constexpr float INV_N = 1.0f / (float)N_H;
    constexpr float CA = 1.0f - 0.01f;
    constexpr float CB = 0.01f;

    // wave-uniform indices -> scalar loads (SGPR-resident p)
    float p[RB_B][RANK];
    #pragma unroll
    for (int j = 0; j < RB_B; ++j)
        #pragma unroll
        for (int r = 0; r < RANK; ++r) {
            float s = Ppart[((size_t)0 * BATCH + b0 + j) * RANK + r]
                    + Ppart[((size_t)1 * BATCH + b0 + j) * RANK + r];
            p[j][r] = s * (CB * INV_N);   // prescale: fold 0.01/N into p
        }

    #pragma unroll
    for (int i = 0; i < ITER_B; ++i) {
        const int c = seg * CSEG_B + i * BLK_B + t;
        float4 f4 = FF4[c];
        float4 u[8];
        #pragma unroll
        for (int k = 0; k < 8; ++k) u[k] = U4[(size_t)c * 8 + k];
        #pragma unroll
        for (int j = 0; j < RB_B; ++j) {
            float4 h4 = H4[(size_t)(b0 + j) * CPR + c];
            float s0 = p[j][0]*u[0].x + p[j][1]*u[0].y + p[j][2]*u[0].z + p[j][3]*u[0].w
                     + p[j][4]*u[1].x + p[j][5]*u[1].y + p[j][6]*u[1].z + p[j][7]*u[1].w;
            float s1 = p[j][0]*u[2].x + p[j][1]*u[2].y + p[j][2]*u[2].z + p[j][3]*u[2].w
                     + p[j][4]*u[3].x + p[j][5]*u[3].y + p[j][6]*u[3].z + p[j][7]*u[3].w;
            float s2 = p[j][0]*u[4].x + p[j][1]*u[4].y + p[j][2]*u[4].z + p[j][3]*u[4].w
                     + p[j][4]*u[5].x + p[j][5]*u[5].y + p[j][6]*u[5].z + p[j][7]*u[5].w;
            float s3 = p[j][0]*u[6].x + p[j][1]*u[6].y + p[j][2]*u[6].z + p[j][3]*u[6].w
                     + p[j][4]*u[7].x + p[j][5]*u[7].y + p[j][6]*u[7].z + p[j][7]*u[7].w;
            float4 o;
            o.x = CA * h4.x + CB * f4.x + s0;
            o.y = CA * h4.y + CB * f4.y + s1;
            o.z = CA * h4.z + CB * f4.z + s2;
            o.w = CA * h4.w + CB * f4.w + s3;
            O4[(size_t)(b0 + j) * CPR + c] = o;
        }
    }
}

extern "C" void kernel_launch(void* const* d_in, const int* in_sizes, int n_in,
                              void* d_out, int out_size, void* d_ws, size_t ws_size,
                              hipStream_t stream) {
    const float* ff = (const float*)d_in[0];   // [8192]
    const float* h  = (const float*)d_in[1];   // [2048, 8192]
    const float* U  = (const float*)d_in[2];   // [8192, 8]
    const float* V  = (const float*)d_in[3];   // [8, 8192]
    float* out = (float*)d_out;                // [2048, 8192]
    float* Ppart = (float*)d_ws;               // [SEG_A][BATCH][RANK] = 128 KB

    rnn_phase1<<<dim3((BATCH / RB_A) * SEG_A), dim3(BLK_A), 0, stream>>>(h, V, Ppart);
    rnn_phase2<<<dim3((BATCH / RB_B) * SEG_B), dim3(BLK_B), 0, stream>>>(ff, h, U, Ppart, out);
}

// Round 6
// 139.308 us; speedup vs baseline: 1.0786x; 1.0280x over previous
//
#include <hip/hip_runtime.h>

#define N_H 8192
#define RANK 8
#define BATCH 2048
#define CPR (N_H / 4)        // 2048 float4 chunks per row

// ---------------- Kernel T: Ut[r][n] = U[n][r] * (0.01/8192)  (coalesced writes)
__global__ __launch_bounds__(256) void rnn_transpose_u(
    const float* __restrict__ U, float* __restrict__ Ut)
{
    constexpr float SCALE = 0.01f / (float)N_H;
    const int i = blockIdx.x * 256 + threadIdx.x;   // i in [0, RANK*N_H)
    const int r = i >> 13;          // i / 8192
    const int n = i & (N_H - 1);    // i % 8192
    Ut[i] = U[(size_t)n * RANK + r] * SCALE;
}

// ---------------- Kernel A: P_part[s][b][r] = sum_{n in seg s} tanh(h[b,n]) * V[r,n]
#define RB_A 4
#define SEG_A 2
#define BLK_A 512
#define CSEG (CPR / SEG_A)           // 1024 float4 per segment
#define ITER_A (CSEG / BLK_A)        // 2
#define NWAVES_A (BLK_A / 64)        // 8

__device__ __forceinline__ float fast_tanh(float x) {
    float e = __expf(2.0f * x);
    return 1.0f - 2.0f / (e + 1.0f);
}

__global__ __launch_bounds__(BLK_A) void rnn_phase1(
    const float* __restrict__ h, const float* __restrict__ V,
    float* __restrict__ Ppart)
{
    const int t = threadIdx.x;
    const int lane = t & 63;
    const int wave = t >> 6;
    const int seg = blockIdx.x & (SEG_A - 1);
    const int b0 = (blockIdx.x >> 1) * RB_A;
    const float4* __restrict__ H4 = (const float4*)h;
    const float4* __restrict__ V4 = (const float4*)V;   // [RANK][CPR]

    float v32[RB_A * RANK];
    #pragma unroll
    for (int k = 0; k < RB_A * RANK; ++k) v32[k] = 0.0f;

    #pragma unroll
    for (int i = 0; i < ITER_A; ++i) {
        const int c = seg * CSEG + i * BLK_A + t;
        float4 v4[RANK];
        #pragma unroll
        for (int r = 0; r < RANK; ++r) v4[r] = V4[r * CPR + c];
        #pragma unroll
        for (int j = 0; j < RB_A; ++j) {
            float4 h4 = H4[(size_t)(b0 + j) * CPR + c];
            float tx = fast_tanh(h4.x), ty = fast_tanh(h4.y);
            float tz = fast_tanh(h4.z), tw = fast_tanh(h4.w);
            #pragma unroll
            for (int r = 0; r < RANK; ++r)
                v32[j * RANK + r] += tx * v4[r].x + ty * v4[r].y
                                   + tz * v4[r].z + tw * v4[r].w;
        }
    }

    // ---- packed wave reduction: 32 values -> lane l holds S_{l&31}
    float v16[16];
    {
        const bool hi = (lane & 1);
        #pragma unroll
        for (int m = 0; m < 16; ++m) {
            float a = v32[2 * m], b = v32[2 * m + 1];
            float keep = hi ? b : a;
            float send = hi ? a : b;
            v16[m] = keep + __shfl_xor(send, 1, 64);
        }
    }
    float v8[8];
    {
        const bool hi = (lane & 2);
        #pragma unroll
        for (int m = 0; m < 8; ++m) {
            float a = v16[2 * m], b = v16[2 * m + 1];
            float keep = hi ? b : a;
            float send = hi ? a : b;
            v8[m] = keep + __shfl_xor(send, 2, 64);
        }
    }
    float v4r[4];
    {
        const bool hi = (lane & 4);
        #pragma unroll
        for (int m = 0; m < 4; ++m) {
            float a = v8[2 * m], b = v8[2 * m + 1];
            float keep = hi ? b : a;
            float send = hi ? a : b;
            v4r[m] = keep + __shfl_xor(send, 4, 64);
        }
    }
    float v2r[2];
    {
        const bool hi = (lane & 8);
        #pragma unroll
        for (int m = 0; m < 2; ++m) {
            float a = v4r[2 * m], b = v4r[2 * m + 1];
            float keep = hi ? b : a;
            float send = hi ? a : b;
            v2r[m] = keep + __shfl_xor(send, 8, 64);
        }
    }
    float v1;
    {
        const bool hi = (lane & 16);
        float a = v2r[0], b = v2r[1];
        float keep = hi ? b : a;
        float send = hi ? a : b;
        v1 = keep + __shfl_xor(send, 16, 64);
    }
    v1 += __shfl_xor(v1, 32, 64);   // lane l (l<32) now holds S_{l&31}

    __shared__ float red[NWAVES_A][32];
    if (lane < 32) red[wave][lane] = v1;
    __syncthreads();
    if (t < 32) {
        float s = 0.0f;
        #pragma unroll
        for (int w = 0; w < NWAVES_A; ++w) s += red[w][t];
        Ppart[((size_t)seg * BATCH + b0 + (t >> 3)) * RANK + (t & 7)] = s;
    }
}

// ---------------- Kernel B: out = 0.99*h + 0.01*ff + sum_r p[b][r]*Ut[r][n]
#define RB_B 4
#define SEG_B 2
#define BLK_B 512
#define CSEG_B (CPR / SEG_B)
#define ITER_B (CSEG_B / BLK_B)      // 2

__global__ __launch_bounds__(BLK_B) void rnn_phase2(
    const float* __restrict__ ff, const float* __restrict__ h,
    const float* __restrict__ Ut, const float* __restrict__ Ppart,
    float* __restrict__ out)
{
    const int t = threadIdx.x;
    const int seg = blockIdx.x & (SEG_B - 1);
    const int b0 = (blockIdx.x >> 1) * RB_B;
    const float4* __restrict__ H4 = (const float4*)h;
    const float4* __restrict__ W4 = (const float4*)Ut;  // [RANK][CPR], prescaled
    const float4* __restrict__ FF4 = (const float4*)ff;
    float4* __restrict__ O4 = (float4*)out;

    constexpr float CA = 1.0f - 0.01f;
    constexpr float CB = 0.01f;

    // wave-uniform indices -> scalar loads (SGPR-resident p); Ut carries the scale
    float p[RB_B][RANK];
    #pragma unroll
    for (int j = 0; j < RB_B; ++j)
        #pragma unroll
        for (int r = 0; r < RANK; ++r)
            p[j][r] = Ppart[((size_t)0 * BATCH + b0 + j) * RANK + r]
                    + Ppart[((size_t)1 * BATCH + b0 + j) * RANK + r];

    #pragma unroll
    for (int i = 0; i < ITER_B; ++i) {
        const int c = seg * CSEG_B + i * BLK_B + t;
        float4 f4 = FF4[c];
        float4 w[RANK];                      // fully coalesced: 1 KB/instruction
        #pragma unroll
        for (int r = 0; r < RANK; ++r) w[r] = W4[r * CPR + c];
        #pragma unroll
        for (int j = 0; j < RB_B; ++j) {
            float4 h4 = H4[(size_t)(b0 + j) * CPR + c];
            float4 o;
            o.x = CA * h4.x + CB * f4.x;
            o.y = CA * h4.y + CB * f4.y;
            o.z = CA * h4.z + CB * f4.z;
            o.w = CA * h4.w + CB * f4.w;
            #pragma unroll
            for (int r = 0; r < RANK; ++r) {
                o.x += p[j][r] * w[r].x;
                o.y += p[j][r] * w[r].y;
                o.z += p[j][r] * w[r].z;
                o.w += p[j][r] * w[r].w;
            }
            O4[(size_t)(b0 + j) * CPR + c] = o;
        }
    }
}

extern "C" void kernel_launch(void* const* d_in, const int* in_sizes, int n_in,
                              void* d_out, int out_size, void* d_ws, size_t ws_size,
                              hipStream_t stream) {
    const float* ff = (const float*)d_in[0];   // [8192]
    const float* h  = (const float*)d_in[1];   // [2048, 8192]
    const float* U  = (const float*)d_in[2];   // [8192, 8]
    const float* V  = (const float*)d_in[3];   // [8, 8192]
    float* out = (float*)d_out;                // [2048, 8192]

    float* Ut    = (float*)d_ws;                          // [RANK][N_H] = 256 KB
    float* Ppart = (float*)((char*)d_ws + RANK * N_H * sizeof(float)); // [SEG][BATCH][RANK]

    rnn_transpose_u<<<dim3((RANK * N_H) / 256), dim3(256), 0, stream>>>(U, Ut);
    rnn_phase1<<<dim3((BATCH / RB_A) * SEG_A), dim3(BLK_A), 0, stream>>>(h, V, Ppart);
    rnn_phase2<<<dim3((BATCH / RB_B) * SEG_B), dim3(BLK_B), 0, stream>>>(ff, h, Ut, Ppart, out);
}

// Round 7
// 137.751 us; speedup vs baseline: 1.0908x; 1.0113x over previous
//
#include <hip/hip_runtime.h>

#define N_H 8192
#define RANK 8
#define BATCH 2048
#define CPR (N_H / 4)      // 2048 float4 chunks per row
#define BLK 512
#define RB 4               // rows per block
#define ITER (CPR / BLK)   // 4 chunks per thread per row
#define NW (BLK / 64)      // 8 waves

// ---------------- Kernel T: Ut[r][n] = U[n][r] * (0.01/8192)
__global__ __launch_bounds__(256) void rnn_transpose_u(
    const float* __restrict__ U, float* __restrict__ Ut)
{
    constexpr float SCALE = 0.01f / (float)N_H;
    const int i = blockIdx.x * 256 + threadIdx.x;   // [0, RANK*N_H)
    const int r = i >> 13;
    const int n = i & (N_H - 1);
    Ut[i] = U[(size_t)n * RANK + r] * SCALE;
}

__device__ __forceinline__ float fast_tanh(float x) {
    float e = __expf(2.0f * x);
    return 1.0f - 2.0f / (e + 1.0f);
}

// ---------------- Fused: phase1 (P = tanh(h)·V^T) + phase3 (epilogue)
__global__ __launch_bounds__(BLK, 4) void rnn_fused(
    const float* __restrict__ ff, const float* __restrict__ h,
    const float* __restrict__ Ut, const float* __restrict__ V,
    float* __restrict__ out)
{
    const int t = threadIdx.x;
    const int lane = t & 63;
    const int wave = t >> 6;
    const int b0 = blockIdx.x * RB;
    const float4* __restrict__ H4 = (const float4*)h;
    const float4* __restrict__ V4 = (const float4*)V;   // [RANK][CPR]
    const float4* __restrict__ W4 = (const float4*)Ut;  // [RANK][CPR], prescaled
    const float4* __restrict__ FF4 = (const float4*)ff;
    float4* __restrict__ O4 = (float4*)out;

    // ---- Phase 1: per-thread partials over full rows (ITER=4 steady-state)
    float v32[RB * RANK];
    #pragma unroll
    for (int k = 0; k < RB * RANK; ++k) v32[k] = 0.0f;

    float4 hc[RB];
    #pragma unroll
    for (int j = 0; j < RB; ++j) hc[j] = H4[(size_t)(b0 + j) * CPR + t];

    #pragma unroll
    for (int i = 0; i < ITER; ++i) {
        const int c = i * BLK + t;
        float4 v4[RANK];
        #pragma unroll
        for (int r = 0; r < RANK; ++r) v4[r] = V4[r * CPR + c];
        float4 hn[RB];
        if (i + 1 < ITER) {              // prefetch next h chunk (HBM latency)
            #pragma unroll
            for (int j = 0; j < RB; ++j)
                hn[j] = H4[(size_t)(b0 + j) * CPR + c + BLK];
        }
        #pragma unroll
        for (int j = 0; j < RB; ++j) {
            float tx = fast_tanh(hc[j].x), ty = fast_tanh(hc[j].y);
            float tz = fast_tanh(hc[j].z), tw = fast_tanh(hc[j].w);
            #pragma unroll
            for (int r = 0; r < RANK; ++r)
                v32[j * RANK + r] += tx * v4[r].x + ty * v4[r].y
                                   + tz * v4[r].z + tw * v4[r].w;
        }
        if (i + 1 < ITER) {
            #pragma unroll
            for (int j = 0; j < RB; ++j) hc[j] = hn[j];
        }
    }

    // ---- packed wave reduction: 32 values -> lane l holds S_{l&31}
    float v16[16];
    {
        const bool hi = (lane & 1);
        #pragma unroll
        for (int m = 0; m < 16; ++m) {
            float a = v32[2 * m], b = v32[2 * m + 1];
            float keep = hi ? b : a;
            float send = hi ? a : b;
            v16[m] = keep + __shfl_xor(send, 1, 64);
        }
    }
    float v8[8];
    {
        const bool hi = (lane & 2);
        #pragma unroll
        for (int m = 0; m < 8; ++m) {
            float a = v16[2 * m], b = v16[2 * m + 1];
            float keep = hi ? b : a;
            float send = hi ? a : b;
            v8[m] = keep + __shfl_xor(send, 2, 64);
        }
    }
    float v4r[4];
    {
        const bool hi = (lane & 4);
        #pragma unroll
        for (int m = 0; m < 4; ++m) {
            float a = v8[2 * m], b = v8[2 * m + 1];
            float keep = hi ? b : a;
            float send = hi ? a : b;
            v4r[m] = keep + __shfl_xor(send, 4, 64);
        }
    }
    float v2r[2];
    {
        const bool hi = (lane & 8);
        #pragma unroll
        for (int m = 0; m < 2; ++m) {
            float a = v4r[2 * m], b = v4r[2 * m + 1];
            float keep = hi ? b : a;
            float send = hi ? a : b;
            v2r[m] = keep + __shfl_xor(send, 8, 64);
        }
    }
    float v1;
    {
        const bool hi = (lane & 16);
        float a = v2r[0], b = v2r[1];
        float keep = hi ? b : a;
        float send = hi ? a : b;
        v1 = keep + __shfl_xor(send, 16, 64);
    }
    v1 += __shfl_xor(v1, 32, 64);   // lane l (l<32) holds S_{l&31}

    // ---- cross-wave combine -> Pp[32] in LDS
    __shared__ float red[NW][32];
    __shared__ float Pp[RB * RANK];
    if (lane < 32) red[wave][lane] = v1;
    __syncthreads();
    if (t < 32) {
        float s = 0.0f;
        #pragma unroll
        for (int w = 0; w < NW; ++w) s += red[w][t];
        Pp[t] = s;   // index k = j*RANK + r
    }
    __syncthreads();

    float p[RB][RANK];
    #pragma unroll
    for (int j = 0; j < RB; ++j)
        #pragma unroll
        for (int r = 0; r < RANK; ++r) p[j][r] = Pp[j * RANK + r];  // broadcast

    // ---- Phase 3: out = 0.99*h + 0.01*ff + sum_r p*Ut  (h re-read is L2-hot)
    constexpr float CA = 1.0f - 0.01f;
    constexpr float CB = 0.01f;

    #pragma unroll
    for (int i = 0; i < ITER; ++i) {
        const int c = i * BLK + t;
        float4 f4 = FF4[c];
        float4 w[RANK];
        #pragma unroll
        for (int r = 0; r < RANK; ++r) w[r] = W4[r * CPR + c];
        #pragma unroll
        for (int j = 0; j < RB; ++j) {
            float4 h4 = H4[(size_t)(b0 + j) * CPR + c];
            float4 o;
            o.x = CA * h4.x + CB * f4.x;
            o.y = CA * h4.y + CB * f4.y;
            o.z = CA * h4.z + CB * f4.z;
            o.w = CA * h4.w + CB * f4.w;
            #pragma unroll
            for (int r = 0; r < RANK; ++r) {
                o.x += p[j][r] * w[r].x;
                o.y += p[j][r] * w[r].y;
                o.z += p[j][r] * w[r].z;
                o.w += p[j][r] * w[r].w;
            }
            O4[(size_t)(b0 + j) * CPR + c] = o;
        }
    }
}

extern "C" void kernel_launch(void* const* d_in, const int* in_sizes, int n_in,
                              void* d_out, int out_size, void* d_ws, size_t ws_size,
                              hipStream_t stream) {
    const float* ff = (const float*)d_in[0];   // [8192]
    const float* h  = (const float*)d_in[1];   // [2048, 8192]
    const float* U  = (const float*)d_in[2];   // [8192, 8]
    const float* V  = (const float*)d_in[3];   // [8, 8192]
    float* out = (float*)d_out;                // [2048, 8192]
    float* Ut  = (float*)d_ws;                 // [RANK][N_H] = 256 KB

    rnn_transpose_u<<<dim3((RANK * N_H) / 256), dim3(256), 0, stream>>>(U, Ut);
    rnn_fused<<<dim3(BATCH / RB), dim3(BLK), 0, stream>>>(ff, h, Ut, V, out);
}